// Round 3
// baseline (460.814 us; speedup 1.0000x reference)
//
#include <hip/hip_runtime.h>
#include <hip/hip_bf16.h>

#define N 8192
#define IN_F 512
#define OUT_F 64
#define S_SPLIT 16
#define JT (N / S_SPLIT)   // 512 columns per split
#define NB (N / 8)         // 1024 mask bytes per row

typedef __attribute__((ext_vector_type(8))) short short8;
typedef __attribute__((ext_vector_type(4))) float floatx4;
typedef __attribute__((ext_vector_type(4))) int intx4;

__device__ inline short f2bf(float x) {
    __hip_bfloat16 b = __float2bfloat16(x);
    return __builtin_bit_cast(short, b);
}

// K0: pack adjacency int32 {0,1} -> bitmask, 1 bit/col. Pure stream kernel.
// thread t covers columns [t*32, t*32+32): writes one uint. bit j of byte bi
// corresponds to column bi*8 + j.
__global__ __launch_bounds__(256) void k_pack(const int* __restrict__ adj,
                                              unsigned* __restrict__ mask) {
    int t = blockIdx.x * 256 + threadIdx.x;      // 2M threads
    const int* p = adj + (size_t)t * 32;
    unsigned b = 0;
#pragma unroll
    for (int c = 0; c < 8; c++) {
        intx4 v = *(const intx4*)(p + c * 4);
#pragma unroll
        for (int j = 0; j < 4; j++)
            b |= (v[j] > 0 ? 1u : 0u) << (c * 4 + j);
    }
    mask[t] = b;
}

// K1a: W [512][64] fp32 -> WT [64][512] bf16 (feature-major for B-fragments)
__global__ void k_wt(const float* __restrict__ W, short* __restrict__ WT) {
    int idx = blockIdx.x * 256 + threadIdx.x;    // 32768 total
    int k = idx >> 6, f = idx & 63;
    WT[f * IN_F + k] = f2bf(W[k * OUT_F + f]);
}

// K1: WH = h @ W via bf16 MFMA. 512 blocks x 1 wave, 16 rows each.
__global__ __launch_bounds__(64) void k_wh(const float* __restrict__ h,
                                           const short* __restrict__ WT,
                                           float* __restrict__ WH,
                                           short* __restrict__ WHbT) {
    __shared__ float tile[OUT_F][17];
    int lane = threadIdx.x;
    int n = lane & 15, q = lane >> 4;
    int i0 = blockIdx.x * 16;
    int rowA = i0 + n;
    const float* hp = h + (size_t)rowA * IN_F + q * 8;
    floatx4 acc[4] = {};
    for (int k0 = 0; k0 < IN_F; k0 += 32) {
        floatx4 h0 = *(const floatx4*)(hp + k0);
        floatx4 h1 = *(const floatx4*)(hp + k0 + 4);
        short8 af;
#pragma unroll
        for (int j = 0; j < 4; j++) { af[j] = f2bf(h0[j]); af[j + 4] = f2bf(h1[j]); }
#pragma unroll
        for (int b = 0; b < 4; b++) {
            short8 bf_ = *(const short8*)(WT + (b * 16 + n) * IN_F + k0 + q * 8);
            acc[b] = __builtin_amdgcn_mfma_f32_16x16x32_bf16(af, bf_, acc[b], 0, 0, 0);
        }
    }
#pragma unroll
    for (int b = 0; b < 4; b++) {
#pragma unroll
        for (int r = 0; r < 4; r++) {
            int rl = q * 4 + r;
            int col = b * 16 + n;
            float v = acc[b][r];
            WH[(i0 + rl) * OUT_F + col] = v;
            tile[col][rl] = v;
        }
    }
    __syncthreads();
    const float* tc = tile[lane];
    short8 s0, s1;
#pragma unroll
    for (int k = 0; k < 8; k++) { s0[k] = f2bf(tc[k]); s1[k] = f2bf(tc[k + 8]); }
    *(short8*)(WHbT + (size_t)lane * N + i0) = s0;
    *(short8*)(WHbT + (size_t)lane * N + i0 + 8) = s1;
}

// K1b: wh1[i] = WH[i,:]·a[:64], wh2[i] = WH[i,:]·a[64:]
__global__ void k_wh12(const float* __restrict__ WH, const float* __restrict__ a,
                       float* __restrict__ wh1, float* __restrict__ wh2) {
    int row = blockIdx.x * 256 + threadIdx.x;
    float s1 = 0.f, s2 = 0.f;
#pragma unroll 8
    for (int f = 0; f < OUT_F; f++) {
        float v = WH[row * OUT_F + f];
        s1 += v * a[f];
        s2 += v * a[OUT_F + f];
    }
    wh1[row] = s1;
    wh2[row] = s2;
}

// K2: fused mask + leaky_relu + exp + (P @ WH) partials, reading the bitmask.
// One dwordx4 of mask per lane covers the whole 512-col split: dword s holds
// the bits for step s; bit (q*8+jj) is column j0 + s*32 + q*8 + jj.
__global__ __launch_bounds__(256, 4) void k_attn(const unsigned char* __restrict__ mask,
                                                 const short* __restrict__ WHbT,
                                                 const float* __restrict__ wh1,
                                                 const float* __restrict__ wh2,
                                                 float* __restrict__ num_part,
                                                 float* __restrict__ den_part) {
    int w = threadIdx.x >> 6;
    int lane = threadIdx.x & 63;
    int n = lane & 15, q = lane >> 4;
    int i0 = blockIdx.x * 64 + w * 16;
    int rowA = i0 + n;
    int split = blockIdx.y;
    int j0 = split * JT;

    // 64B of mask: all bits this lane's row needs for this split
    const intx4* mp = (const intx4*)(mask + (size_t)rowA * NB + (j0 >> 3));
    intx4 mdw0 = mp[0], mdw1 = mp[1], mdw2 = mp[2], mdw3 = mp[3];

    const float* w2p = wh2 + j0 + q * 8;
    const short* bp0 = WHbT + (size_t)n * N + j0 + q * 8;
    float my_wh1 = wh1[rowA];

    floatx4 acc[4] = {};
    float dsum = 0.f;
    int qs = q * 8;

#pragma unroll
    for (int s = 0; s < 16; s++) {
        unsigned md = (unsigned)((s < 4) ? mdw0[s] : (s < 8) ? mdw1[s - 4]
                               : (s < 12) ? mdw2[s - 8] : mdw3[s - 12]);
        floatx4 w20 = *(const floatx4*)(w2p + s * 32);
        floatx4 w21 = *(const floatx4*)(w2p + s * 32 + 4);
        short8 bfr[4];
#pragma unroll
        for (int b = 0; b < 4; b++)
            bfr[b] = *(const short8*)(bp0 + (size_t)b * 16 * N + s * 32);

        float p[8];
#pragma unroll
        for (int jj = 0; jj < 8; jj++) {
            float e = my_wh1 + ((jj < 4) ? w20[jj] : w21[jj - 4]);
            float el = fmaxf(e, 0.01f * e);        // leaky_relu
            float pv = __expf(el);
            pv = ((md >> (qs + jj)) & 1u) ? pv : 0.f;
            p[jj] = pv;
            dsum += pv;
        }
        short8 af;
#pragma unroll
        for (int jj = 0; jj < 8; jj++) af[jj] = f2bf(p[jj]);
#pragma unroll
        for (int b = 0; b < 4; b++)
            acc[b] = __builtin_amdgcn_mfma_f32_16x16x32_bf16(af, bfr[b], acc[b], 0, 0, 0);
    }

    dsum += __shfl_xor(dsum, 16, 64);
    dsum += __shfl_xor(dsum, 32, 64);
    if (q == 0) den_part[(size_t)split * N + rowA] = dsum;

    float* np_ = num_part + (size_t)split * N * OUT_F;
#pragma unroll
    for (int b = 0; b < 4; b++)
#pragma unroll
        for (int r = 0; r < 4; r++)
            np_[(i0 + q * 4 + r) * OUT_F + b * 16 + n] = acc[b][r];
}

// K3: out = elu( (Σ num_part) / (Σ den_part) )
__global__ void k_final(const float* __restrict__ num_part,
                        const float* __restrict__ den_part,
                        float* __restrict__ out) {
    int idx = blockIdx.x * 256 + threadIdx.x;    // 524288 total
    int row = idx >> 6;
    float s = 0.f, d = 0.f;
#pragma unroll
    for (int sp = 0; sp < S_SPLIT; sp++) {
        s += num_part[(size_t)sp * N * OUT_F + idx];
        d += den_part[sp * N + row];
    }
    float x = s / d;
    out[idx] = (x > 0.f) ? x : (__expf(x) - 1.f);
}

extern "C" void kernel_launch(void* const* d_in, const int* in_sizes, int n_in,
                              void* d_out, int out_size, void* d_ws, size_t ws_size,
                              hipStream_t stream) {
    const float* h = (const float*)d_in[0];
    const int* adj = (const int*)d_in[1];
    const float* W = (const float*)d_in[2];
    const float* a = (const float*)d_in[3];
    float* out = (float*)d_out;

    char* ws = (char*)d_ws;
    float* WH       = (float*)(ws);                                   // 2 MB
    short* WHbT     = (short*)(ws + (size_t)(2 << 20));                // 1 MB
    short* WT       = (short*)(ws + (size_t)(3 << 20));                // 64 KB
    float* wh1      = (float*)(ws + (size_t)(3 << 20) + (64 << 10));   // 32 KB
    float* wh2      = wh1 + N;                                         // 32 KB
    unsigned* maskb = (unsigned*)(ws + (size_t)(4 << 20));             // 8 MB
    float* num_p    = (float*)(ws + (size_t)(16 << 20));               // 32 MB
    float* den_p    = (float*)(ws + (size_t)(48 << 20));               // 512 KB

    k_pack<<<dim3((N / 8 * N / 4) / 256), dim3(256), 0, stream>>>(adj, maskb);
    k_wt<<<dim3(128), dim3(256), 0, stream>>>(W, WT);
    k_wh<<<dim3(N / 16), dim3(64), 0, stream>>>(h, WT, WH, WHbT);
    k_wh12<<<dim3(N / 256), dim3(256), 0, stream>>>(WH, a, wh1, wh2);
    k_attn<<<dim3(128, S_SPLIT), dim3(256), 0, stream>>>((const unsigned char*)maskb,
                                                         WHbT, wh1, wh2, num_p, den_p);
    k_final<<<dim3((N * OUT_F) / 256), dim3(256), 0, stream>>>(num_p, den_p, out);
}

// Round 4
// 420.638 us; speedup vs baseline: 1.0955x; 1.0955x over previous
//
#include <hip/hip_runtime.h>
#include <hip/hip_bf16.h>

#define N 8192
#define IN_F 512
#define OUT_F 64
#define S_SPLIT 16
#define JT (N / S_SPLIT)   // 512 columns per split
#define NB (N / 8)         // 1024 mask bytes per row
#define LDP 520            // LDS row pitch in shorts (512 + 8 pad)

typedef __attribute__((ext_vector_type(8))) short short8;
typedef __attribute__((ext_vector_type(4))) float floatx4;
typedef __attribute__((ext_vector_type(4))) int intx4;

__device__ inline short f2bf(float x) {
    __hip_bfloat16 b = __float2bfloat16(x);
    return __builtin_bit_cast(short, b);
}

// K0: pack adjacency int32 {0,1} -> bitmask, 1 bit/col. Pure stream kernel.
// thread t covers columns [t*32, t*32+32); bit j of dword = col t*32+j.
__global__ __launch_bounds__(256) void k_pack(const int* __restrict__ adj,
                                              unsigned* __restrict__ mask) {
    int t = blockIdx.x * 256 + threadIdx.x;      // 2M threads
    const int* p = adj + (size_t)t * 32;
    unsigned b = 0;
#pragma unroll
    for (int c = 0; c < 8; c++) {
        intx4 v = *(const intx4*)(p + c * 4);
#pragma unroll
        for (int j = 0; j < 4; j++)
            b |= (v[j] > 0 ? 1u : 0u) << (c * 4 + j);
    }
    mask[t] = b;
}

// K1a: W [512][64] fp32 -> WT [64][512] bf16
__global__ void k_wt(const float* __restrict__ W, short* __restrict__ WT) {
    int idx = blockIdx.x * 256 + threadIdx.x;    // 32768 total
    int k = idx >> 6, f = idx & 63;
    WT[f * IN_F + k] = f2bf(W[k * OUT_F + f]);
}

// K1: WH = h @ W via bf16 MFMA. 512 blocks x 1 wave, 16 rows each.
// Epilogue: WHbT bf16 [64][8192] (LDS transpose) + wh1/wh2 (folded k_wh12).
__global__ __launch_bounds__(64) void k_wh(const float* __restrict__ h,
                                           const short* __restrict__ WT,
                                           const float* __restrict__ a,
                                           short* __restrict__ WHbT,
                                           float* __restrict__ wh1,
                                           float* __restrict__ wh2) {
    __shared__ float tile[OUT_F][17];
    int lane = threadIdx.x;
    int n = lane & 15, q = lane >> 4;
    int i0 = blockIdx.x * 16;
    int rowA = i0 + n;
    const float* hp = h + (size_t)rowA * IN_F + q * 8;
    floatx4 acc[4] = {};
    for (int k0 = 0; k0 < IN_F; k0 += 32) {
        floatx4 h0 = *(const floatx4*)(hp + k0);
        floatx4 h1 = *(const floatx4*)(hp + k0 + 4);
        short8 af;
#pragma unroll
        for (int j = 0; j < 4; j++) { af[j] = f2bf(h0[j]); af[j + 4] = f2bf(h1[j]); }
#pragma unroll
        for (int b = 0; b < 4; b++) {
            short8 bf_ = *(const short8*)(WT + (b * 16 + n) * IN_F + k0 + q * 8);
            acc[b] = __builtin_amdgcn_mfma_f32_16x16x32_bf16(af, bf_, acc[b], 0, 0, 0);
        }
    }
    // C/D layout: col = b*16 + (lane&15), row-local = q*4 + r
    // (a) transpose to WHbT via LDS
#pragma unroll
    for (int b = 0; b < 4; b++)
#pragma unroll
        for (int r = 0; r < 4; r++)
            tile[b * 16 + n][q * 4 + r] = acc[b][r];
    // (b) wh1/wh2: lane partial over its 4 feature-cols, butterfly over n
    float a1v[4], a2v[4];
#pragma unroll
    for (int b = 0; b < 4; b++) { a1v[b] = a[b * 16 + n]; a2v[b] = a[OUT_F + b * 16 + n]; }
#pragma unroll
    for (int r = 0; r < 4; r++) {
        float s1 = 0.f, s2 = 0.f;
#pragma unroll
        for (int b = 0; b < 4; b++) { s1 += acc[b][r] * a1v[b]; s2 += acc[b][r] * a2v[b]; }
#pragma unroll
        for (int m = 1; m <= 8; m <<= 1) {
            s1 += __shfl_xor(s1, m, 64);
            s2 += __shfl_xor(s2, m, 64);
        }
        if (n == 0) {
            wh1[i0 + q * 4 + r] = s1;
            wh2[i0 + q * 4 + r] = s2;
        }
    }
    __syncthreads();
    const float* tc = tile[lane];
    short8 s0, s1v;
#pragma unroll
    for (int k = 0; k < 8; k++) { s0[k] = f2bf(tc[k]); s1v[k] = f2bf(tc[k + 8]); }
    *(short8*)(WHbT + (size_t)lane * N + i0) = s0;
    *(short8*)(WHbT + (size_t)lane * N + i0 + 8) = s1v;
}

// K2: fused mask + leaky_relu + exp + (P @ WH) partials.
// Grid (32 row-blocks, 16 splits) x 256 thr. Wave owns 64 rows (4 A-frags);
// B-tile WHbT[0..63][j0..j0+511] staged once in padded LDS, reused by all
// 4 waves and all 4 row-frags.
__global__ __launch_bounds__(256) void k_attn(const unsigned char* __restrict__ mask,
                                              const short* __restrict__ WHbT,
                                              const float* __restrict__ wh1,
                                              const float* __restrict__ wh2,
                                              float* __restrict__ num_part,
                                              float* __restrict__ den_part) {
    __shared__ short ldsb[OUT_F * LDP];          // 66.5 KB
    int tid = threadIdx.x;
    int w = tid >> 6;
    int lane = tid & 63;
    int n = lane & 15, q = lane >> 4;
    int split = blockIdx.y;
    int j0 = split * JT;
    int i0 = blockIdx.x * 256 + w * 64;          // wave's first row

    // ---- stage B-tile: WHbT[f][j0..j0+511] -> ldsb[f*LDP + c], coalesced
#pragma unroll
    for (int l = 0; l < 16; l++) {
        int idx = l * 256 + tid;                 // 0..4095
        int f = idx >> 6, c16 = idx & 63;        // 64 chunks of 8 shorts per row
        short8 v = *(const short8*)(WHbT + (size_t)f * N + j0 + c16 * 8);
        *(short8*)(ldsb + f * LDP + c16 * 8) = v;
    }
    __syncthreads();

    // ---- per-rowfrag mask (64B each) + wh1
    intx4 mrf[4];
    float wh1f[4];
#pragma unroll
    for (int rf = 0; rf < 4; rf++) {
        int rowA = i0 + rf * 16 + n;
        wh1f[rf] = wh1[rowA];
    }

    floatx4 acc[4][4] = {};                       // [rf][b]
    float dsum[4] = {0.f, 0.f, 0.f, 0.f};
    const float* w2p = wh2 + j0 + q * 8;
    const short* lp = ldsb + q * 8;               // + b*16*LDP + n*LDP + s*32
    int qs = q * 8;

    for (int g = 0; g < 4; g++) {                 // 4 groups of 4 steps
#pragma unroll
        for (int rf = 0; rf < 4; rf++) {
            int rowA = i0 + rf * 16 + n;
            mrf[rf] = *(const intx4*)(mask + (size_t)rowA * NB + split * 64 + g * 16);
        }
#pragma unroll
        for (int d = 0; d < 4; d++) {
            int s = g * 4 + d;
            floatx4 w20 = *(const floatx4*)(w2p + s * 32);
            floatx4 w21 = *(const floatx4*)(w2p + s * 32 + 4);
            short8 bfr[4];
#pragma unroll
            for (int b = 0; b < 4; b++)
                bfr[b] = *(const short8*)(lp + (b * 16 + n) * LDP + s * 32);
#pragma unroll
            for (int rf = 0; rf < 4; rf++) {
                unsigned md = (unsigned)mrf[rf][d];
                float p[8];
#pragma unroll
                for (int jj = 0; jj < 8; jj++) {
                    float e = wh1f[rf] + ((jj < 4) ? w20[jj] : w21[jj - 4]);
                    float el = fmaxf(e, 0.01f * e);     // leaky_relu
                    float pv = __expf(el);
                    pv = ((md >> (qs + jj)) & 1u) ? pv : 0.f;
                    p[jj] = pv;
                    dsum[rf] += pv;
                }
                short8 af;
#pragma unroll
                for (int jj = 0; jj < 8; jj++) af[jj] = f2bf(p[jj]);
#pragma unroll
                for (int b = 0; b < 4; b++)
                    acc[rf][b] = __builtin_amdgcn_mfma_f32_16x16x32_bf16(af, bfr[b], acc[rf][b], 0, 0, 0);
            }
        }
    }

    // denominators: combine 4 q-groups holding the same row
#pragma unroll
    for (int rf = 0; rf < 4; rf++) {
        float d = dsum[rf];
        d += __shfl_xor(d, 16, 64);
        d += __shfl_xor(d, 32, 64);
        if (q == 0) den_part[(size_t)split * N + i0 + rf * 16 + n] = d;
    }

    // numerators: C/D layout row = q*4+r, col = b*16+n
    float* np_ = num_part + (size_t)split * N * OUT_F;
#pragma unroll
    for (int rf = 0; rf < 4; rf++)
#pragma unroll
        for (int b = 0; b < 4; b++)
#pragma unroll
            for (int r = 0; r < 4; r++)
                np_[(size_t)(i0 + rf * 16 + q * 4 + r) * OUT_F + b * 16 + n] = acc[rf][b][r];
}

// K3: out = elu( (Σ num_part) / (Σ den_part) )
__global__ void k_final(const float* __restrict__ num_part,
                        const float* __restrict__ den_part,
                        float* __restrict__ out) {
    int idx = blockIdx.x * 256 + threadIdx.x;    // 524288 total
    int row = idx >> 6;
    float s = 0.f, d = 0.f;
#pragma unroll
    for (int sp = 0; sp < S_SPLIT; sp++) {
        s += num_part[(size_t)sp * N * OUT_F + idx];
        d += den_part[sp * N + row];
    }
    float x = s / d;
    out[idx] = (x > 0.f) ? x : (__expf(x) - 1.f);
}

extern "C" void kernel_launch(void* const* d_in, const int* in_sizes, int n_in,
                              void* d_out, int out_size, void* d_ws, size_t ws_size,
                              hipStream_t stream) {
    const float* h = (const float*)d_in[0];
    const int* adj = (const int*)d_in[1];
    const float* W = (const float*)d_in[2];
    const float* a = (const float*)d_in[3];
    float* out = (float*)d_out;

    char* ws = (char*)d_ws;
    short* WHbT     = (short*)(ws);                                  // 1 MB
    short* WT       = (short*)(ws + (size_t)(1 << 20));              // 64 KB
    float* wh1      = (float*)(ws + (size_t)(1 << 20) + (64 << 10)); // 32 KB
    float* wh2      = wh1 + N;                                       // 32 KB
    unsigned* maskb = (unsigned*)(ws + (size_t)(2 << 20));           // 8 MB
    float* num_p    = (float*)(ws + (size_t)(16 << 20));             // 32 MB
    float* den_p    = (float*)(ws + (size_t)(48 << 20));             // 512 KB

    k_pack<<<dim3((N / 32) * (N / 256)), dim3(256), 0, stream>>>(adj, maskb);
    k_wt<<<dim3(128), dim3(256), 0, stream>>>(W, WT);
    k_wh<<<dim3(N / 16), dim3(64), 0, stream>>>(h, WT, a, WHbT, wh1, wh2);
    k_attn<<<dim3(N / 256, S_SPLIT), dim3(256), 0, stream>>>((const unsigned char*)maskb,
                                                             WHbT, wh1, wh2, num_p, den_p);
    k_final<<<dim3((N * OUT_F) / 256), dim3(256), 0, stream>>>(num_p, den_p, out);
}

// Round 5
// 411.059 us; speedup vs baseline: 1.1210x; 1.0233x over previous
//
#include <hip/hip_runtime.h>
#include <hip/hip_bf16.h>

#define N 8192
#define IN_F 512
#define OUT_F 64
#define S_SPLIT 16
#define JT (N / S_SPLIT)   // 512 columns per split
#define NB (N / 8)         // 1024 mask bytes per row
#define LDP 520            // LDS row pitch in shorts (512 + 8 pad, 16B-aligned)

typedef __attribute__((ext_vector_type(8))) short short8;
typedef __attribute__((ext_vector_type(4))) float floatx4;
typedef __attribute__((ext_vector_type(4))) int intx4;

__device__ inline short f2bf(float x) {
    __hip_bfloat16 b = __float2bfloat16(x);
    return __builtin_bit_cast(short, b);
}

// K0: pack adjacency int32 {0,1} -> bitmask via ballot. Wave handles 512
// consecutive flat elements: 8 coalesced dword loads (256B each), 8 ballots
// (bit i of ballot j = element base + j*64 + i -> exactly mask bit order),
// lanes 0..15 store the 64B result.
__global__ __launch_bounds__(256) void k_pack(const int* __restrict__ adj,
                                              unsigned* __restrict__ mask) {
    int wv = (blockIdx.x * 256 + threadIdx.x) >> 6;   // global wave id
    int lane = threadIdx.x & 63;
    const int* p = adj + (size_t)wv * 512 + lane;
    unsigned long long m0 = __ballot(p[0]   > 0);
    unsigned long long m1 = __ballot(p[64]  > 0);
    unsigned long long m2 = __ballot(p[128] > 0);
    unsigned long long m3 = __ballot(p[192] > 0);
    unsigned long long m4 = __ballot(p[256] > 0);
    unsigned long long m5 = __ballot(p[320] > 0);
    unsigned long long m6 = __ballot(p[384] > 0);
    unsigned long long m7 = __ballot(p[448] > 0);
    if (lane < 16) {
        // lane d writes dword d of the 64B block: qword d>>1, half d&1
        unsigned long long s0 = (lane & 2) ? m1 : m0;
        unsigned long long s1 = (lane & 2) ? m3 : m2;
        unsigned long long s2 = (lane & 2) ? m5 : m4;
        unsigned long long s3 = (lane & 2) ? m7 : m6;
        unsigned long long t0 = (lane & 4) ? s1 : s0;
        unsigned long long t1 = (lane & 4) ? s3 : s2;
        unsigned long long u  = (lane & 8) ? t1 : t0;
        unsigned dw = (lane & 1) ? (unsigned)(u >> 32) : (unsigned)u;
        mask[wv * 16 + lane] = dw;
    }
}

// K1a: W [512][64] fp32 -> WT [64][512] bf16
__global__ void k_wt(const float* __restrict__ W, short* __restrict__ WT) {
    int idx = blockIdx.x * 256 + threadIdx.x;    // 32768 total
    int k = idx >> 6, f = idx & 63;
    WT[f * IN_F + k] = f2bf(W[k * OUT_F + f]);
}

// K1: WH = h @ W via bf16 MFMA. 512 blocks x 1 wave, 16 rows each.
// Epilogue: WHbT bf16 [64][8192] (LDS transpose) + wh1/wh2 (folded).
__global__ __launch_bounds__(64) void k_wh(const float* __restrict__ h,
                                           const short* __restrict__ WT,
                                           const float* __restrict__ a,
                                           short* __restrict__ WHbT,
                                           float* __restrict__ wh1,
                                           float* __restrict__ wh2) {
    __shared__ float tile[OUT_F][17];
    int lane = threadIdx.x;
    int n = lane & 15, q = lane >> 4;
    int i0 = blockIdx.x * 16;
    int rowA = i0 + n;
    const float* hp = h + (size_t)rowA * IN_F + q * 8;
    floatx4 acc[4] = {};
    for (int k0 = 0; k0 < IN_F; k0 += 32) {
        floatx4 h0 = *(const floatx4*)(hp + k0);
        floatx4 h1 = *(const floatx4*)(hp + k0 + 4);
        short8 af;
#pragma unroll
        for (int j = 0; j < 4; j++) { af[j] = f2bf(h0[j]); af[j + 4] = f2bf(h1[j]); }
#pragma unroll
        for (int b = 0; b < 4; b++) {
            short8 bf_ = *(const short8*)(WT + (b * 16 + n) * IN_F + k0 + q * 8);
            acc[b] = __builtin_amdgcn_mfma_f32_16x16x32_bf16(af, bf_, acc[b], 0, 0, 0);
        }
    }
#pragma unroll
    for (int b = 0; b < 4; b++)
#pragma unroll
        for (int r = 0; r < 4; r++)
            tile[b * 16 + n][q * 4 + r] = acc[b][r];
    float a1v[4], a2v[4];
#pragma unroll
    for (int b = 0; b < 4; b++) { a1v[b] = a[b * 16 + n]; a2v[b] = a[OUT_F + b * 16 + n]; }
#pragma unroll
    for (int r = 0; r < 4; r++) {
        float s1 = 0.f, s2 = 0.f;
#pragma unroll
        for (int b = 0; b < 4; b++) { s1 += acc[b][r] * a1v[b]; s2 += acc[b][r] * a2v[b]; }
#pragma unroll
        for (int m = 1; m <= 8; m <<= 1) {
            s1 += __shfl_xor(s1, m, 64);
            s2 += __shfl_xor(s2, m, 64);
        }
        if (n == 0) {
            wh1[i0 + q * 4 + r] = s1;
            wh2[i0 + q * 4 + r] = s2;
        }
    }
    __syncthreads();
    const float* tc = tile[lane];
    short8 s0, s1v;
#pragma unroll
    for (int k = 0; k < 8; k++) { s0[k] = f2bf(tc[k]); s1v[k] = f2bf(tc[k + 8]); }
    *(short8*)(WHbT + (size_t)lane * N + i0) = s0;
    *(short8*)(WHbT + (size_t)lane * N + i0 + 8) = s1v;
}

// K2: fused mask + leaky_relu + exp + (P @ WH) partials.
// Grid (32, 16) x 256 thr; wave owns 64 rows; B-tile in LDS (66.5 KB ->
// 2 blocks/CU). launch_bounds(256,2): 256-VGPR budget, no spills.
__global__ __launch_bounds__(256, 2) void k_attn(const unsigned char* __restrict__ mask,
                                                 const short* __restrict__ WHbT,
                                                 const float* __restrict__ wh1,
                                                 const float* __restrict__ wh2,
                                                 float* __restrict__ num_part,
                                                 float* __restrict__ den_part) {
    __shared__ short ldsb[OUT_F * LDP];          // 66.5 KB
    int tid = threadIdx.x;
    int w = tid >> 6;
    int lane = tid & 63;
    int n = lane & 15, q = lane >> 4;
    int split = blockIdx.y;
    int j0 = split * JT;
    int i0 = blockIdx.x * 256 + w * 64;          // wave's first row

    // stage B-tile: each wave reads one full WHbT row (1KB) per iteration
#pragma unroll
    for (int l = 0; l < 16; l++) {
        int idx = l * 256 + tid;
        int f = idx >> 6, c16 = idx & 63;
        short8 v = *(const short8*)(WHbT + (size_t)f * N + j0 + c16 * 8);
        *(short8*)(ldsb + f * LDP + c16 * 8) = v;
    }
    __syncthreads();

    float wh1f[4];
#pragma unroll
    for (int rf = 0; rf < 4; rf++) wh1f[rf] = wh1[i0 + rf * 16 + n];

    floatx4 acc[4][4] = {};                       // [rf][b]
    float dsum[4] = {0.f, 0.f, 0.f, 0.f};
    const float* w2p = wh2 + j0 + q * 8;
    const short* lp = ldsb + q * 8;
    int qs = q * 8;

    // mask double-buffer across g-groups
    intx4 mcur[4], mnxt[4];
#pragma unroll
    for (int rf = 0; rf < 4; rf++)
        mcur[rf] = *(const intx4*)(mask + (size_t)(i0 + rf * 16 + n) * NB + split * 64);

    for (int g = 0; g < 4; g++) {
        if (g < 3) {
#pragma unroll
            for (int rf = 0; rf < 4; rf++)
                mnxt[rf] = *(const intx4*)(mask + (size_t)(i0 + rf * 16 + n) * NB
                                           + split * 64 + (g + 1) * 16);
        }
#pragma unroll
        for (int d = 0; d < 4; d++) {
            int s = g * 4 + d;
            floatx4 w20 = *(const floatx4*)(w2p + s * 32);
            floatx4 w21 = *(const floatx4*)(w2p + s * 32 + 4);
            short8 bfr[4];
#pragma unroll
            for (int b = 0; b < 4; b++)
                bfr[b] = *(const short8*)(lp + (b * 16 + n) * LDP + s * 32);
#pragma unroll
            for (int rf = 0; rf < 4; rf++) {
                unsigned md = (unsigned)mcur[rf][d];
                float p[8];
#pragma unroll
                for (int jj = 0; jj < 8; jj++) {
                    float e = wh1f[rf] + ((jj < 4) ? w20[jj] : w21[jj - 4]);
                    float el = fmaxf(e, 0.01f * e);     // leaky_relu
                    float pv = __expf(el);
                    pv = ((md >> (qs + jj)) & 1u) ? pv : 0.f;
                    p[jj] = pv;
                    dsum[rf] += pv;
                }
                short8 af;
#pragma unroll
                for (int jj = 0; jj < 8; jj++) af[jj] = f2bf(p[jj]);
#pragma unroll
                for (int b = 0; b < 4; b++)
                    acc[rf][b] = __builtin_amdgcn_mfma_f32_16x16x32_bf16(af, bfr[b], acc[rf][b], 0, 0, 0);
            }
        }
#pragma unroll
        for (int rf = 0; rf < 4; rf++) mcur[rf] = mnxt[rf];
    }

#pragma unroll
    for (int rf = 0; rf < 4; rf++) {
        float d = dsum[rf];
        d += __shfl_xor(d, 16, 64);
        d += __shfl_xor(d, 32, 64);
        if (q == 0) den_part[(size_t)split * N + i0 + rf * 16 + n] = d;
    }

    float* np_ = num_part + (size_t)split * N * OUT_F;
#pragma unroll
    for (int rf = 0; rf < 4; rf++)
#pragma unroll
        for (int b = 0; b < 4; b++)
#pragma unroll
            for (int r = 0; r < 4; r++)
                np_[(size_t)(i0 + rf * 16 + q * 4 + r) * OUT_F + b * 16 + n] = acc[rf][b][r];
}

// K3: out = elu( (Σ num_part) / (Σ den_part) )
__global__ void k_final(const float* __restrict__ num_part,
                        const float* __restrict__ den_part,
                        float* __restrict__ out) {
    int idx = blockIdx.x * 256 + threadIdx.x;    // 524288 total
    int row = idx >> 6;
    float s = 0.f, d = 0.f;
#pragma unroll
    for (int sp = 0; sp < S_SPLIT; sp++) {
        s += num_part[(size_t)sp * N * OUT_F + idx];
        d += den_part[sp * N + row];
    }
    float x = s / d;
    out[idx] = (x > 0.f) ? x : (__expf(x) - 1.f);
}

extern "C" void kernel_launch(void* const* d_in, const int* in_sizes, int n_in,
                              void* d_out, int out_size, void* d_ws, size_t ws_size,
                              hipStream_t stream) {
    const float* h = (const float*)d_in[0];
    const int* adj = (const int*)d_in[1];
    const float* W = (const float*)d_in[2];
    const float* a = (const float*)d_in[3];
    float* out = (float*)d_out;

    char* ws = (char*)d_ws;
    short* WHbT     = (short*)(ws);                                  // 1 MB
    short* WT       = (short*)(ws + (size_t)(1 << 20));              // 64 KB
    float* wh1      = (float*)(ws + (size_t)(1 << 20) + (64 << 10)); // 32 KB
    float* wh2      = wh1 + N;                                       // 32 KB
    unsigned* maskb = (unsigned*)(ws + (size_t)(2 << 20));           // 8 MB
    float* num_p    = (float*)(ws + (size_t)(16 << 20));             // 32 MB
    float* den_p    = (float*)(ws + (size_t)(48 << 20));             // 512 KB

    k_pack<<<dim3((N / 32) * (N / 256) * 4), dim3(256), 0, stream>>>(adj, maskb);
    k_wt<<<dim3(128), dim3(256), 0, stream>>>(W, WT);
    k_wh<<<dim3(N / 16), dim3(64), 0, stream>>>(h, WT, a, WHbT, wh1, wh2);
    k_attn<<<dim3(N / 256, S_SPLIT), dim3(256), 0, stream>>>((const unsigned char*)maskb,
                                                             WHbT, wh1, wh2, num_p, den_p);
    k_final<<<dim3((N * OUT_F) / 256), dim3(256), 0, stream>>>(num_p, den_p, out);
}